// Round 1
// baseline (1576.439 us; speedup 1.0000x reference)
//
#include <hip/hip_runtime.h>
#include <cstdint>
#include <cstddef>

// Problem constants (from reference): B=4,S=1024 -> T=4096 tokens
#define T_TOK 4096
#define DDIM 1024
#define HDIM 4096
#define NEXP 8
#define NSHARED 2
#define NPASS 10   // 2 shared + 8 routing expert passes

typedef unsigned short ushort_t;
typedef __attribute__((ext_vector_type(8))) short short8;   // 8 bf16 = 4 VGPRs (MFMA A/B frag)
typedef __attribute__((ext_vector_type(4))) float f32x4;    // MFMA C/D frag

// fp32 -> bf16 round-to-nearest-even
__device__ inline ushort_t f2bf(float f) {
  unsigned u = __float_as_uint(f);
  u += 0x7fffu + ((u >> 16) & 1u);
  return (ushort_t)(u >> 16);
}

// async global->LDS, 16B per lane (global_load_lds_dwordx4).
// LDS dest MUST be wave-uniform base + lane*16 (guide m104/m108).
__device__ inline void async_copy16(const ushort_t* g, ushort_t* l) {
  __builtin_amdgcn_global_load_lds(
      (const __attribute__((address_space(1))) void*)g,
      (__attribute__((address_space(3))) void*)l, 16, 0, 0);
}

// JAX default gelu: tanh approximation. Stable tanh form (no inf/inf).
__device__ inline float gelu_tanh(float x) {
  float u = 0.7978845608028654f * (x + 0.044715f * x * x * x);
  float th = 1.0f - 2.0f / (__expf(2.0f * u) + 1.0f);
  return 0.5f * x * (1.0f + th);
}

// ---------------- router: top-2 of (x@Wr + br + gumbel) per token --------
// softmax/TEMP are monotonic -> top-k on raw perturbed logits. One wave/token.
__global__ __launch_bounds__(256) void router_kernel(
    const float* __restrict__ x, const float* __restrict__ Wr,
    const float* __restrict__ br, const float* __restrict__ gum,
    int* __restrict__ mask) {
  int lane = threadIdx.x & 63;
  int wv = blockIdx.x * 4 + (threadIdx.x >> 6);
  if (wv >= T_TOK) return;
  const float* xr = x + (long)wv * DDIM;
  float acc[NEXP] = {0.f, 0.f, 0.f, 0.f, 0.f, 0.f, 0.f, 0.f};
  for (int d = lane; d < DDIM; d += 64) {
    float xv = xr[d];
    const float* w = Wr + d * NEXP;
#pragma unroll
    for (int e = 0; e < NEXP; e++) acc[e] += xv * w[e];
  }
#pragma unroll
  for (int e = 0; e < NEXP; e++) {
    float v = acc[e];
#pragma unroll
    for (int o = 32; o > 0; o >>= 1) v += __shfl_down(v, o);
    acc[e] = v;
  }
  if (lane == 0) {
    float vals[NEXP];
#pragma unroll
    for (int e = 0; e < NEXP; e++) vals[e] = acc[e] + br[e] + gum[(long)wv * NEXP + e];
    // top-2, first-index-on-tie (matches lax.top_k)
    int i1 = 0; float b1 = vals[0];
#pragma unroll
    for (int e = 1; e < NEXP; e++) if (vals[e] > b1) { b1 = vals[e]; i1 = e; }
    int i2 = 0; float b2 = -3.4e38f;
#pragma unroll
    for (int e = 0; e < NEXP; e++) if (e != i1 && vals[e] > b2) { b2 = vals[e]; i2 = e; }
    mask[wv] = (1 << i1) | (1 << i2);
  }
}

// ---------------- cast x fp32 -> bf16 (float4 loads, 8B stores) ----------
__global__ __launch_bounds__(256) void cast_x_kernel(
    const float* __restrict__ in, ushort_t* __restrict__ out, int n4) {
  int i = blockIdx.x * 256 + threadIdx.x;
  if (i >= n4) return;
  float4 v = ((const float4*)in)[i];
  ushort4 o = make_ushort4(f2bf(v.x), f2bf(v.y), f2bf(v.z), f2bf(v.w));
  ((ushort4*)out)[i] = o;
}

// ---------------- transpose+cast: in fp32 [R][C] -> out bf16 [C][R] ------
// So GEMM B-operand is [N][K] row-major -> ds_read_b128 fragments.
__global__ __launch_bounds__(256) void transpose_cast(
    const float* __restrict__ in, ushort_t* __restrict__ out, int R, int C) {
  __shared__ float tile[32][33];  // +1 pad breaks bank conflicts
  long zoff = (long)blockIdx.z * R * C;
  in += zoff; out += zoff;
  int c0 = blockIdx.x * 32, r0 = blockIdx.y * 32;
  int tx = threadIdx.x, ty = threadIdx.y;  // block (32,8)
#pragma unroll
  for (int k = 0; k < 4; k++)
    tile[ty + 8 * k][tx] = in[(long)(r0 + ty + 8 * k) * C + (c0 + tx)];
  __syncthreads();
#pragma unroll
  for (int k = 0; k < 4; k++)
    out[(long)(c0 + ty + 8 * k) * R + (r0 + tx)] = f2bf(tile[tx][ty + 8 * k]);
}

// ---------------- GEMM: C[M,N] = A[M,K] @ Bt[N,K]^T  (bf16 MFMA) ---------
// m97-style: 128x128 tile, BK=32, 256 threads = 4 waves (2x2 of 64x64),
// each wave 4x4 tiles of 16x16x32 MFMA, global_load_lds width=16 staging.
// MODE 1: outH = bf16(gelu(C + bias))            (GEMM1 -> h)
// MODE 2: if selected: atomicAdd(outF, C [+bias]) (GEMM2 -> out)
template <int MODE>
__global__ __launch_bounds__(256) void gemm_kernel(
    const ushort_t* __restrict__ A, const ushort_t* __restrict__ Wt,
    const float* __restrict__ biasS, const float* __restrict__ biasE,
    ushort_t* __restrict__ outH, float* __restrict__ outF,
    const int* __restrict__ mask, int N, int K, int pBase, int splitK,
    long strideA, long strideO) {
  __shared__ ushort_t As[128 * 32];
  __shared__ ushort_t Bs[128 * 32];

  int tid = threadIdx.x;
  int zz = blockIdx.z;
  int p = pBase + zz / splitK;     // expert-pass index 0..9
  int kc = zz % splitK;            // split-K chunk
  const ushort_t* Ap = A + (long)p * strideA;
  const ushort_t* Bp = Wt + (long)p * (long)N * K;
  const float* bias =
      (p < NSHARED) ? (biasS + (long)p * N) : (biasE + (long)(p - NSHARED) * N);
  int selBit = (MODE == 2 && p >= NSHARED) ? (p - NSHARED) : -1;

  int kLen = K / splitK;
  int kStart = kc * kLen;
  int row0 = blockIdx.y * 128;
  int col0 = blockIdx.x * 128;

  // staging map: thread t loads 16B at tile row t/4, k-offset (t%4)*8
  int tq = tid & 3;
  int tr = tid >> 2;
  const ushort_t* aS = Ap + (long)(row0 + tr) * K + kStart + tq * 8;
  const ushort_t* bS = Bp + (long)(col0 + tr) * K + kStart + tq * 8;
  ushort_t* aD = As + tid * 8;
  ushort_t* bD = Bs + tid * 8;
  long half = (long)64 * K;

  int lane = tid & 63;
  int wv = tid >> 6;
  int wr = wv >> 1, wc = wv & 1;
  int ln = lane & 15, quad = lane >> 4;

  f32x4 acc[4][4] = {};

  const ushort_t* aLds = As + (wr * 64 + ln) * 32 + quad * 8;
  const ushort_t* bLds = Bs + (wc * 64 + ln) * 32 + quad * 8;

  for (int k0 = 0; k0 < kLen; k0 += 32) {
    async_copy16(aS, aD);
    async_copy16(aS + half, aD + 2048);
    async_copy16(bS, bD);
    async_copy16(bS + half, bD + 2048);
    __syncthreads();  // drains vmcnt before LDS reads
    short8 af[4], bf[4];
#pragma unroll
    for (int i = 0; i < 4; i++) {
      af[i] = *(const short8*)(aLds + i * 16 * 32);
      bf[i] = *(const short8*)(bLds + i * 16 * 32);
    }
#pragma unroll
    for (int i = 0; i < 4; i++)
#pragma unroll
      for (int j = 0; j < 4; j++)
        acc[i][j] = __builtin_amdgcn_mfma_f32_16x16x32_bf16(af[i], bf[j],
                                                            acc[i][j], 0, 0, 0);
    __syncthreads();  // protect LDS before next stage
    aS += 32;
    bS += 32;
  }

  // epilogue: C/D layout col=lane&15, row=quad*4+reg (guide m89/m91)
#pragma unroll
  for (int i = 0; i < 4; i++) {
    int rowB = row0 + wr * 64 + i * 16 + quad * 4;
#pragma unroll
    for (int j = 0; j < 4; j++) {
      int col = col0 + wc * 64 + j * 16 + ln;
#pragma unroll
      for (int r = 0; r < 4; r++) {
        int t = rowB + r;
        float v = acc[i][j][r];
        if (MODE == 1) {
          v = gelu_tanh(v + bias[col]);
          outH[(long)p * strideO + (long)t * N + col] = f2bf(v);
        } else {
          bool sel = (selBit < 0) || ((mask[t] >> selBit) & 1);
          if (sel) {
            if (kc == 0) v += bias[col];
            atomicAdd(&outF[(long)t * N + col], v);
          }
        }
      }
    }
  }
}

extern "C" void kernel_launch(void* const* d_in, const int* in_sizes, int n_in,
                              void* d_out, int out_size, void* d_ws,
                              size_t ws_size, hipStream_t stream) {
  const float* x   = (const float*)d_in[0];
  const float* Ws1 = (const float*)d_in[1];
  const float* bs1 = (const float*)d_in[2];
  const float* Ws2 = (const float*)d_in[3];
  const float* bs2 = (const float*)d_in[4];
  const float* We1 = (const float*)d_in[5];
  const float* be1 = (const float*)d_in[6];
  const float* We2 = (const float*)d_in[7];
  const float* be2 = (const float*)d_in[8];
  const float* Wr  = (const float*)d_in[9];
  const float* br  = (const float*)d_in[10];
  const float* gum = (const float*)d_in[11];
  float* out = (float*)d_out;

  // workspace layout
  char* ws = (char*)d_ws;
  size_t off = 0;
  int* mask = (int*)(ws + off); off += 32768;
  ushort_t* xb = (ushort_t*)(ws + off); off += (size_t)T_TOK * DDIM * 2;
  ushort_t* W1t = (ushort_t*)(ws + off); off += (size_t)NPASS * HDIM * DDIM * 2;
  ushort_t* W2t = (ushort_t*)(ws + off); off += (size_t)NPASS * DDIM * HDIM * 2;
  ushort_t* h = (ushort_t*)(ws + off);
  size_t hBatchBytes = (size_t)NPASS * T_TOK * HDIM * 2;  // 335 MB
  bool batched = (ws_size >= off + hBatchBytes);          // else: 33.5 MB h, sequential

  hipMemsetAsync(d_out, 0, (size_t)T_TOK * DDIM * sizeof(float), stream);
  router_kernel<<<T_TOK / 4, 256, 0, stream>>>(x, Wr, br, gum, mask);
  cast_x_kernel<<<(T_TOK * DDIM / 4 + 255) / 256, 256, 0, stream>>>(
      x, xb, T_TOK * DDIM / 4);
  // W1 set: [D][H] -> bf16 [H][D]
  transpose_cast<<<dim3(HDIM / 32, DDIM / 32, NSHARED), dim3(32, 8), 0, stream>>>(
      Ws1, W1t, DDIM, HDIM);
  transpose_cast<<<dim3(HDIM / 32, DDIM / 32, NEXP), dim3(32, 8), 0, stream>>>(
      We1, W1t + (size_t)NSHARED * HDIM * DDIM, DDIM, HDIM);
  // W2 set: [H][D] -> bf16 [D][H]
  transpose_cast<<<dim3(DDIM / 32, HDIM / 32, NSHARED), dim3(32, 8), 0, stream>>>(
      Ws2, W2t, HDIM, DDIM);
  transpose_cast<<<dim3(DDIM / 32, HDIM / 32, NEXP), dim3(32, 8), 0, stream>>>(
      We2, W2t + (size_t)NSHARED * DDIM * HDIM, HDIM, DDIM);

  if (batched) {
    // all 10 passes in one launch each; GEMM2 races handled by atomicAdd
    gemm_kernel<1><<<dim3(HDIM / 128, T_TOK / 128, NPASS), 256, 0, stream>>>(
        xb, W1t, bs1, be1, h, nullptr, nullptr, HDIM, DDIM, 0, 1, 0L,
        (long)T_TOK * HDIM);
    gemm_kernel<2><<<dim3(DDIM / 128, T_TOK / 128, NPASS), 256, 0, stream>>>(
        h, W2t, bs2, be2, nullptr, out, mask, DDIM, HDIM, 0, 1,
        (long)T_TOK * HDIM, 0L);
  } else {
    // sequential passes, single h buffer; split-K=2 on GEMM2 for occupancy
    for (int p = 0; p < NPASS; p++) {
      gemm_kernel<1><<<dim3(HDIM / 128, T_TOK / 128, 1), 256, 0, stream>>>(
          xb, W1t, bs1, be1, h, nullptr, nullptr, HDIM, DDIM, p, 1, 0L, 0L);
      gemm_kernel<2><<<dim3(DDIM / 128, T_TOK / 128, 2), 256, 0, stream>>>(
          h, W2t, bs2, be2, nullptr, out, mask, DDIM, HDIM, p, 2, 0L, 0L);
    }
  }
  (void)in_sizes; (void)n_in; (void)out_size;
}

// Round 2
// 1157.817 us; speedup vs baseline: 1.3616x; 1.3616x over previous
//
#include <hip/hip_runtime.h>
#include <cstdint>
#include <cstddef>

// Problem constants: B=4,S=1024 -> T=4096 tokens
#define T_TOK 4096
#define DDIM 1024
#define HDIM 4096
#define NEXP 8
#define NSHARED 2

typedef unsigned short ushort_t;
typedef __attribute__((ext_vector_type(8))) short short8;   // 8 bf16 (MFMA A/B frag)
typedef __attribute__((ext_vector_type(4))) float f32x4;    // MFMA C/D frag

__device__ inline ushort_t f2bf(float f) {
  unsigned u = __float_as_uint(f);
  u += 0x7fffu + ((u >> 16) & 1u);
  return (ushort_t)(u >> 16);
}

// async global->LDS 16B/lane. LDS dest must be wave-uniform base + lane*16;
// the GLOBAL source may be per-lane arbitrary (gather is legal).
__device__ inline void async_copy16(const ushort_t* g, ushort_t* l) {
  __builtin_amdgcn_global_load_lds(
      (const __attribute__((address_space(1))) void*)g,
      (__attribute__((address_space(3))) void*)l, 16, 0, 0);
}

// JAX default gelu (tanh approx), overflow-safe tanh form
__device__ inline float gelu_tanh(float x) {
  float u = 0.7978845608028654f * (x + 0.044715f * x * x * x);
  float th = 1.0f - 2.0f / (__expf(2.0f * u) + 1.0f);
  return 0.5f * x * (1.0f + th);
}

// ---------------- router: top-2 of (x@Wr + br + gumbel); count per expert ---
__global__ __launch_bounds__(256) void router_kernel(
    const float* __restrict__ x, const float* __restrict__ Wr,
    const float* __restrict__ br, const float* __restrict__ gum,
    int* __restrict__ choice, int* __restrict__ cnt) {
  int lane = threadIdx.x & 63;
  int wv = blockIdx.x * 4 + (threadIdx.x >> 6);
  if (wv >= T_TOK) return;
  const float* xr = x + (long)wv * DDIM;
  float acc[NEXP] = {0.f, 0.f, 0.f, 0.f, 0.f, 0.f, 0.f, 0.f};
  for (int d = lane; d < DDIM; d += 64) {
    float xv = xr[d];
    const float* w = Wr + d * NEXP;
#pragma unroll
    for (int e = 0; e < NEXP; e++) acc[e] += xv * w[e];
  }
#pragma unroll
  for (int e = 0; e < NEXP; e++) {
    float v = acc[e];
#pragma unroll
    for (int o = 32; o > 0; o >>= 1) v += __shfl_down(v, o);
    acc[e] = v;
  }
  if (lane == 0) {
    float vals[NEXP];
#pragma unroll
    for (int e = 0; e < NEXP; e++) vals[e] = acc[e] + br[e] + gum[(long)wv * NEXP + e];
    int i1 = 0; float b1 = vals[0];
#pragma unroll
    for (int e = 1; e < NEXP; e++) if (vals[e] > b1) { b1 = vals[e]; i1 = e; }
    int i2 = -1; float b2 = -3.4e38f;
#pragma unroll
    for (int e = 0; e < NEXP; e++) if (e != i1 && vals[e] > b2) { b2 = vals[e]; i2 = e; }
    choice[wv] = i1 | (i2 << 4);
    atomicAdd(&cnt[i1], 1);
    atomicAdd(&cnt[i2], 1);
  }
}

// ---------------- prefix: 128-aligned segment base per expert --------------
__global__ void prefix_kernel(const int* __restrict__ cnt, int* __restrict__ base,
                              int* __restrict__ fill) {
  if (threadIdx.x == 0 && blockIdx.x == 0) {
    int off = 0;
    for (int e = 0; e < NEXP; e++) {
      base[e] = off;
      off += (cnt[e] + 127) & ~127;
      fill[e] = 0;
    }
  }
}

// ---------------- scatter token ids into per-expert compact lists ----------
__global__ __launch_bounds__(256) void scatter_kernel(
    const int* __restrict__ choice, const int* __restrict__ base,
    int* __restrict__ fill, int* __restrict__ idx) {
  int t = blockIdx.x * 256 + threadIdx.x;
  if (t >= T_TOK) return;
  int c = choice[t];
  int e1 = c & 15, e2 = (c >> 4) & 15;
  int p1 = atomicAdd(&fill[e1], 1);
  idx[base[e1] + p1] = t;
  int p2 = atomicAdd(&fill[e2], 1);
  idx[base[e2] + p2] = t;
}

// ---------------- cast x fp32 -> bf16 --------------------------------------
__global__ __launch_bounds__(256) void cast_x_kernel(
    const float* __restrict__ in, ushort_t* __restrict__ out, int n4) {
  int i = blockIdx.x * 256 + threadIdx.x;
  if (i >= n4) return;
  float4 v = ((const float4*)in)[i];
  ushort4 o = make_ushort4(f2bf(v.x), f2bf(v.y), f2bf(v.z), f2bf(v.w));
  ((ushort4*)out)[i] = o;
}

// ---------------- transpose+cast: fp32 [R][C] -> bf16 [C][R] ---------------
__global__ __launch_bounds__(256) void transpose_cast(
    const float* __restrict__ in, ushort_t* __restrict__ out, int R, int C) {
  __shared__ float tile[32][33];
  long zoff = (long)blockIdx.z * R * C;
  in += zoff; out += zoff;
  int c0 = blockIdx.x * 32, r0 = blockIdx.y * 32;
  int tx = threadIdx.x, ty = threadIdx.y;  // block (32,8)
#pragma unroll
  for (int k = 0; k < 4; k++)
    tile[ty + 8 * k][tx] = in[(long)(r0 + ty + 8 * k) * C + (c0 + tx)];
  __syncthreads();
#pragma unroll
  for (int k = 0; k < 4; k++)
    out[(long)(c0 + ty + 8 * k) * R + (r0 + tx)] = f2bf(tile[tx][ty + 8 * k]);
}

// ---------------- GEMM core: 128x128 tile, BK=32, bf16 16x16x32 MFMA -------
// MODE 0: shared GEMM1  h_sh[4096][8192] = gelu(xb @ W1t[0:8192]^T + bs1)
// MODE 1: shared GEMM2  out += h_sh @ cat_K(W2t[0],W2t[1])^T (+bs2 sum), splitK=4
// MODE 2: routing GEMM1 (gather rows by token): h_rt = gelu(xb[idx] @ W1t[e]^T + be1[e])
// MODE 3: routing GEMM2 (scatter-add): out[tok] += h_rt[e] @ W2t[e]^T (+be2[e]), splitK=2
template <int MODE>
__global__ __launch_bounds__(256) void gemm_kernel(
    const ushort_t* __restrict__ A, const ushort_t* __restrict__ W,
    const float* __restrict__ bias, ushort_t* __restrict__ outH,
    float* __restrict__ outF, const int* __restrict__ cnt,
    const int* __restrict__ base, const int* __restrict__ idx) {
  __shared__ ushort_t As[128 * 32];
  __shared__ ushort_t Bs[128 * 32];

  int tid = threadIdx.x;
  int row0 = blockIdx.y * 128;
  int col0 = blockIdx.x * 128;

  int e = 0, kc = 0, M = 0, base_e = 0;
  const ushort_t* Ap;
  const ushort_t* Bp;
  long lda, ldb;
  int kLen, kStartA, kStartB;

  if (MODE == 0) {
    Ap = A; lda = DDIM; kStartA = 0;
    Bp = W; ldb = DDIM; kStartB = 0; kLen = DDIM;
  } else if (MODE == 1) {
    kc = blockIdx.z;                 // 0..3, 2048-wide K chunks of K=8192
    int s = kc >> 1;                 // which shared expert's W2
    Ap = A; lda = 2 * HDIM; kStartA = kc * 2048;
    Bp = W + (long)s * DDIM * HDIM; ldb = HDIM; kStartB = (kc & 1) * 2048;
    kLen = 2048;
  } else if (MODE == 2) {
    e = blockIdx.z; M = cnt[e];
    if (row0 >= M) return;
    base_e = base[e];
    Ap = A; lda = DDIM; kStartA = 0;
    Bp = W + (long)(NSHARED + e) * HDIM * DDIM; ldb = DDIM; kStartB = 0;
    kLen = DDIM;
  } else {
    e = blockIdx.z >> 1; kc = blockIdx.z & 1; M = cnt[e];
    if (row0 >= M) return;
    base_e = base[e];
    Ap = A + (long)base_e * HDIM; lda = HDIM; kStartA = kc * 2048;
    Bp = W + (long)(NSHARED + e) * DDIM * HDIM; ldb = HDIM; kStartB = kc * 2048;
    kLen = 2048;
  }

  // staging map: thread t loads 16B at tile row t/4, k-offset (t%4)*8; x2 rows
  int tq = tid & 3, tr = tid >> 2;
  const ushort_t* aS;
  const ushort_t* aS2;
  if (MODE == 2) {
    int s1 = row0 + tr;       if (s1 > M - 1) s1 = M - 1;
    int s2 = row0 + tr + 64;  if (s2 > M - 1) s2 = M - 1;
    aS  = Ap + (long)idx[base_e + s1] * lda + kStartA + tq * 8;
    aS2 = Ap + (long)idx[base_e + s2] * lda + kStartA + tq * 8;
  } else {
    aS  = Ap + (long)(row0 + tr) * lda + kStartA + tq * 8;
    aS2 = aS + 64L * lda;
  }
  const ushort_t* bS  = Bp + (long)(col0 + tr) * ldb + kStartB + tq * 8;
  const ushort_t* bS2 = bS + 64L * ldb;
  ushort_t* aD = As + tid * 8;
  ushort_t* bD = Bs + tid * 8;

  int lane = tid & 63;
  int wv = tid >> 6;
  int wr = wv >> 1, wc = wv & 1;
  int ln = lane & 15, quad = lane >> 4;

  f32x4 acc[4][4] = {};
  const ushort_t* aLds = As + (wr * 64 + ln) * 32 + quad * 8;
  const ushort_t* bLds = Bs + (wc * 64 + ln) * 32 + quad * 8;

  for (int k0 = 0; k0 < kLen; k0 += 32) {
    async_copy16(aS, aD);
    async_copy16(aS2, aD + 2048);
    async_copy16(bS, bD);
    async_copy16(bS2, bD + 2048);
    __syncthreads();
    short8 af[4], bf[4];
#pragma unroll
    for (int i = 0; i < 4; i++) {
      af[i] = *(const short8*)(aLds + i * 16 * 32);
      bf[i] = *(const short8*)(bLds + i * 16 * 32);
    }
#pragma unroll
    for (int i = 0; i < 4; i++)
#pragma unroll
      for (int j = 0; j < 4; j++)
        acc[i][j] = __builtin_amdgcn_mfma_f32_16x16x32_bf16(af[i], bf[j],
                                                            acc[i][j], 0, 0, 0);
    __syncthreads();
    aS += 32; aS2 += 32; bS += 32; bS2 += 32;
  }

  // epilogue: C/D layout col=lane&15, row=quad*4+reg
#pragma unroll
  for (int i = 0; i < 4; i++) {
    int rowB = row0 + wr * 64 + i * 16 + quad * 4;
#pragma unroll
    for (int j = 0; j < 4; j++) {
      int col = col0 + wc * 64 + j * 16 + ln;
#pragma unroll
      for (int r = 0; r < 4; r++) {
        int t = rowB + r;
        float v = acc[i][j][r];
        if (MODE == 0) {
          outH[(long)t * (2 * HDIM) + col] = f2bf(gelu_tanh(v + bias[col]));
        } else if (MODE == 1) {
          if (kc == 0) v += bias[col] + bias[DDIM + col];
          atomicAdd(outF + (long)t * DDIM + col, v);
        } else if (MODE == 2) {
          if (t < M)
            outH[((long)base_e + t) * HDIM + col] =
                f2bf(gelu_tanh(v + bias[(long)e * HDIM + col]));
        } else {
          if (t < M) {
            int tok = idx[base_e + t];
            if (kc == 0) v += bias[(long)e * DDIM + col];
            atomicAdd(outF + (long)tok * DDIM + col, v);
          }
        }
      }
    }
  }
}

extern "C" void kernel_launch(void* const* d_in, const int* in_sizes, int n_in,
                              void* d_out, int out_size, void* d_ws,
                              size_t ws_size, hipStream_t stream) {
  const float* x   = (const float*)d_in[0];
  const float* Ws1 = (const float*)d_in[1];
  const float* bs1 = (const float*)d_in[2];
  const float* Ws2 = (const float*)d_in[3];
  const float* bs2 = (const float*)d_in[4];
  const float* We1 = (const float*)d_in[5];
  const float* be1 = (const float*)d_in[6];
  const float* We2 = (const float*)d_in[7];
  const float* be2 = (const float*)d_in[8];
  const float* Wr  = (const float*)d_in[9];
  const float* br  = (const float*)d_in[10];
  const float* gum = (const float*)d_in[11];
  float* out = (float*)d_out;

  // ---- workspace layout (~320 MB) ----
  char* ws = (char*)d_ws;
  size_t off = 0;
  int* cnt    = (int*)(ws + off); off += 256;          // 8 counters (zeroed)
  int* base   = (int*)(ws + off); off += 256;          // 8 segment bases
  int* fill   = (int*)(ws + off); off += 256;          // 8 fill cursors
  int* choice = (int*)(ws + off); off += T_TOK * 4;    // packed top-2 per token
  int* idx    = (int*)(ws + off); off += 9216 * 4;     // compact token lists
  off = (off + 255) & ~(size_t)255;
  ushort_t* xb   = (ushort_t*)(ws + off); off += (size_t)T_TOK * DDIM * 2;         // 8 MB
  ushort_t* W1t  = (ushort_t*)(ws + off); off += (size_t)10 * HDIM * DDIM * 2;     // 80 MB
  ushort_t* W2t  = (ushort_t*)(ws + off); off += (size_t)10 * DDIM * HDIM * 2;     // 80 MB
  ushort_t* h_sh = (ushort_t*)(ws + off); off += (size_t)T_TOK * 2 * HDIM * 2;     // 64 MB
  ushort_t* h_rt = (ushort_t*)(ws + off); off += (size_t)9216 * HDIM * 2;          // 75.5 MB
  (void)ws_size;

  hipMemsetAsync(out, 0, (size_t)T_TOK * DDIM * sizeof(float), stream);
  hipMemsetAsync(cnt, 0, 256, stream);

  router_kernel<<<T_TOK / 4, 256, 0, stream>>>(x, Wr, br, gum, choice, cnt);
  prefix_kernel<<<1, 64, 0, stream>>>(cnt, base, fill);
  scatter_kernel<<<T_TOK / 256, 256, 0, stream>>>(choice, base, fill, idx);
  cast_x_kernel<<<(T_TOK * DDIM / 4 + 255) / 256, 256, 0, stream>>>(
      x, xb, T_TOK * DDIM / 4);

  // W1: [D][H] -> bf16 [H][D]; shared first (contiguous N=8192 block), then routing
  transpose_cast<<<dim3(HDIM / 32, DDIM / 32, NSHARED), dim3(32, 8), 0, stream>>>(
      Ws1, W1t, DDIM, HDIM);
  transpose_cast<<<dim3(HDIM / 32, DDIM / 32, NEXP), dim3(32, 8), 0, stream>>>(
      We1, W1t + (size_t)NSHARED * HDIM * DDIM, DDIM, HDIM);
  // W2: [H][D] -> bf16 [D][H]
  transpose_cast<<<dim3(DDIM / 32, HDIM / 32, NSHARED), dim3(32, 8), 0, stream>>>(
      Ws2, W2t, HDIM, DDIM);
  transpose_cast<<<dim3(DDIM / 32, HDIM / 32, NEXP), dim3(32, 8), 0, stream>>>(
      We2, W2t + (size_t)NSHARED * DDIM * HDIM, HDIM, DDIM);

  // shared experts, merged: GEMM1 N=8192, GEMM2 K=8192 (splitK=4)
  gemm_kernel<0><<<dim3(2 * HDIM / 128, T_TOK / 128, 1), 256, 0, stream>>>(
      xb, W1t, bs1, h_sh, nullptr, nullptr, nullptr, nullptr);
  // routing experts, sparse: gather GEMM1, scatter GEMM2 (splitK=2)
  gemm_kernel<2><<<dim3(HDIM / 128, T_TOK / 128, NEXP), 256, 0, stream>>>(
      xb, W1t, be1, h_rt, nullptr, cnt, base, idx);
  gemm_kernel<1><<<dim3(DDIM / 128, T_TOK / 128, 4), 256, 0, stream>>>(
      h_sh, W2t, bs2, nullptr, out, nullptr, nullptr, nullptr);
  gemm_kernel<3><<<dim3(DDIM / 128, T_TOK / 128, 2 * NEXP), 256, 0, stream>>>(
      h_rt, W2t, be2, nullptr, out, cnt, base, idx);

  (void)in_sizes; (void)n_in; (void)out_size;
}